// Round 20
// baseline (98.973 us; speedup 1.0000x reference)
//
#include <hip/hip_runtime.h>
#include <stdint.h>
#include <limits.h>

#define BB 64
#define HH 512
#define WW 512
#define WPR 8                  // 64-bit words per row
#define WPRP 9                 // padded LDS stride
#define HWP (HH*WW)            // 262144
#define NPIX (BB*HWP)          // 16777216
#define NROWS (BB*HH)          // 32768
#define RS 128                 // exact max runs/row in opened mask (len>=3, gap>=1)
#define RSP 129                // padded LDS run stride
#define MAXRUNS (NROWS*RS)     // 4194304
#define KPR 32                 // roots threads per row
#define MAXROOTS 2048          // area>=200 roots per image <= 1310

typedef unsigned char u8;
typedef unsigned long long u64;

__device__ __forceinline__ int imax(int a, int b){ return a > b ? a : b; }

// ---------------- threshold + bit-pack, 16 px/thread (full occupancy) -----
__global__ void k_threshpack(const float* __restrict__ x, u64* __restrict__ bits,
                             int* __restrict__ rootcnt){
  int t = blockIdx.x*blockDim.x + threadIdx.x;      // 0 .. NPIX/16
  if (t < BB) rootcnt[t] = 0;
  const float4* X = reinterpret_cast<const float4*>(x) + (size_t)t*4;
  unsigned m = 0;
  #pragma unroll
  for (int q = 0; q < 4; ++q){
    float4 v = X[q];
    m |= (unsigned)(v.x > -0.5f) << (q*4 + 0);
    m |= (unsigned)(v.y > -0.5f) << (q*4 + 1);
    m |= (unsigned)(v.z > -0.5f) << (q*4 + 2);
    m |= (unsigned)(v.w > -0.5f) << (q*4 + 3);
  }
  int sub = t & 3;
  unsigned p1 = __shfl_xor(m, 1);
  unsigned v32 = (sub & 1) ? (p1 | (m << 16)) : (m | (p1 << 16));
  unsigned p2 = __shfl_xor(v32, 2);
  if ((sub & 3) == 0){
    u64 w = (u64)v32 | ((u64)p2 << 32);
    bits[t >> 2] = w;
  }
}

// ---------------- helpers for bit morphology ----------------
__device__ __forceinline__ u64 hshift3_and(u64 c, u64 l, u64 r){
  return c & ((c << 1) | (l >> 63)) & ((c >> 1) | (r << 63));
}
__device__ __forceinline__ u64 hshift3_or(u64 c, u64 l, u64 r){
  return c | (c << 1) | (l >> 63) | (c >> 1) | (r << 63);
}
__device__ __forceinline__ u64 hshift5_and(u64 c, u64 l, u64 r){
  return hshift3_and(c, l, r) & ((c << 2) | (l >> 62)) & ((c >> 2) | (r << 62));
}
__device__ __forceinline__ u64 hshift5_or(u64 c, u64 l, u64 r){
  return hshift3_or(c, l, r) | (c << 2) | (l >> 62) | (c >> 2) | (r << 62);
}

// load word (row, wi) with image-vertical zero pad
__device__ __forceinline__ u64 ldw(const u64* __restrict__ in, int img, int rowInImg, int wi){
  if ((unsigned)rowInImg >= (unsigned)HH) return 0ULL;
  if ((unsigned)wi >= (unsigned)WPR) return 0ULL;
  return in[((size_t)img*HH + rowInImg)*WPR + wi];
}

// ---------------- LDS union-find (slab-local, path halving) ---------------
__device__ __forceinline__ int lfind(int* lp, int p){
  while (true){
    int q = lp[p];
    int g = lp[q];
    if (q == g) return q;
    atomicMin(&lp[p], g);
    p = g;
  }
}
__device__ __forceinline__ void lunion(int* lp, int a, int b){
  while (true){
    a = lfind(lp, a);
    b = lfind(lp, b);
    if (a == b) return;
    if (a < b){ int t = a; a = b; b = t; }
    int old = atomicMin(&lp[a], b);
    if (old == a) return;
    a = old;
  }
}

// ------- open (erode3+dilate3) + runs + slab-local UF (bitmap input) ------
// Split from the round-12..18 mega-fusion: the streaming f32 read runs at
// full occupancy in k_threshpack; this kernel reads the 2 MB bitmap (L2).
#define ORPB 16
#define TPR (256/ORPB)         // 16 threads per row in L/W phases
#define SLABN (ORPB*RS)        // 2048 run slots per slab
__global__ __launch_bounds__(256)
void k_openlocal(const u64* __restrict__ bits, uint32_t* __restrict__ runs,
                 int* __restrict__ cnt, int* __restrict__ parent,
                 int* __restrict__ area, int* __restrict__ clabel){
  __shared__ u64 er[ORPB + 2][WPRP];   // y0-1 .. y0+16
  __shared__ u64 dl[ORPB][WPRP];       // y0   .. y0+15
  __shared__ uint32_t lruns[ORPB][RSP];
  __shared__ int lcnt[ORPB];
  __shared__ int lparent[SLABN];
  int R0 = blockIdx.x * ORPB;
  int img = R0 >> 9;
  int y0 = R0 & (HH - 1);

  // phase E: erode3x3 rows y0-1 .. y0+16 (reads bitmap from L2)
  for (int s = threadIdx.x; s < (ORPB + 2)*WPR; s += 256){
    int j = s >> 3;
    int wi = s & 7;
    int yy = y0 - 1 + j;
    u64 acc = ~0ULL;
    #pragma unroll
    for (int dy = -1; dy <= 1; ++dy){
      int y = yy + dy;
      u64 c = ldw(bits, img, y, wi);
      u64 l = ldw(bits, img, y, wi - 1);
      u64 r = ldw(bits, img, y, wi + 1);
      acc &= ((unsigned)y < (unsigned)HH) ? hshift3_and(c, l, r) : 0ULL;
    }
    if ((unsigned)yy >= (unsigned)HH) acc = 0ULL;
    er[j][wi] = acc;
  }
  __syncthreads();

  // phase D: dilate3x3 -> dl
  for (int s = threadIdx.x; s < ORPB*WPR; s += 256){
    int ri = s >> 3;
    int wi = s & 7;
    u64 acc = 0ULL;
    #pragma unroll
    for (int dy = 0; dy < 3; ++dy){
      int li = ri + dy;
      u64 c = er[li][wi];
      u64 l = (wi > 0) ? er[li][wi-1] : 0ULL;
      u64 r = (wi < 7) ? er[li][wi+1] : 0ULL;
      acc |= hshift3_or(c, l, r);
    }
    dl[ri][wi] = acc;
  }
  __syncthreads();

  // init local parent (identity)
  for (int i = threadIdx.x; i < SLABN; i += 256) lparent[i] = i;

  // phase R: run extraction, one thread per row
  if (threadIdx.x < ORPB){
    int ri = threadIdx.x;
    int r = R0 + ri;
    u64 w[8];
    #pragma unroll
    for (int i = 0; i < 8; ++i) w[i] = dl[ri][i];
    int base = r*RS;
    int k = 0;
    int pending = -1;
    u64 carry = 0;
    #pragma unroll
    for (int wi = 0; wi < 8; ++wi){
      u64 b = w[wi];
      u64 nb0 = (wi < 7) ? (w[wi+1] & 1ULL) : 0ULL;
      u64 starts = b & ~((b << 1) | carry);
      u64 ends   = b & ~(b >> 1);
      if (nb0) ends &= ~(1ULL << 63);
      carry = b >> 63;
      while (ends){
        int e = __ffsll((long long)ends) - 1; ends &= ends - 1;
        int s;
        if (pending >= 0){ s = pending; pending = -1; }
        else { s = wi*64 + (__ffsll((long long)starts) - 1); starts &= starts - 1; }
        uint32_t rv = (uint32_t)s | ((uint32_t)(wi*64 + e) << 16);
        int id = base + k;
        runs[id] = rv; lruns[ri][k] = rv;
        area[id] = 0; clabel[id] = 0;
        k++;
      }
      if (starts) pending = wi*64 + (__ffsll((long long)starts) - 1);
    }
    cnt[r] = k; lcnt[ri] = k;
  }
  __syncthreads();

  // phase L: local link rows 1..ORPB-1 (TPR threads per row)
  {
    int ri = threadIdx.x / TPR;
    int k0 = threadIdx.x % TPR;
    if (ri > 0){
      int ca = lcnt[ri], cb = lcnt[ri-1];
      if (cb > 0){
        for (int k = k0; k < ca; k += TPR){
          uint32_t ra = lruns[ri][k]; int sA = (int)(ra & 0xffff), eA = (int)(ra >> 16);
          int lo = 0, hi = cb, target = sA - 1;
          while (lo < hi){
            int mid = (lo + hi) >> 1;
            if ((int)(lruns[ri-1][mid] >> 16) < target) lo = mid + 1; else hi = mid;
          }
          for (int j = lo; j < cb; ++j){
            if ((int)(lruns[ri-1][j] & 0xffff) > eA + 1) break;
            lunion(lparent, ri*RS + k, (ri-1)*RS + j);
          }
        }
      }
    }
  }
  __syncthreads();

  // phase W: write global parent = slab root (global id space)
  {
    int ri = threadIdx.x / TPR;
    int k0 = threadIdx.x % TPR;
    int n = lcnt[ri];
    for (int k = k0; k < n; k += TPR){
      int lid = ri*RS + k;
      parent[R0*RS + lid] = R0*RS + lfind(lparent, lid);
    }
  }
}

// ---------------- global union-find (path halving) ----------------
__device__ __forceinline__ int uf_find(int* parent, int p){
  while (true){
    int q = parent[p];
    int g = parent[q];
    if (q == g) return q;
    atomicMin(&parent[p], g);
    p = g;
  }
}
__device__ __forceinline__ void uf_union(int* parent, int a, int b){
  while (true){
    a = uf_find(parent, a);
    b = uf_find(parent, b);
    if (a == b) return;
    if (a < b){ int t = a; a = b; b = t; }
    int old = atomicMin(&parent[a], b);
    if (old == a) return;
    a = old;
  }
}

// read-only find
__device__ __forceinline__ int ro_find(const int* __restrict__ parent, int p){
  while (true){ int q = parent[p]; if (q == p) return p; p = q; }
}

// ---------------- boundary link: only rows at slab seams ------------------
#define NBND (HH/ORPB - 1)     // 31 per image
__global__ void k_linkb(const uint32_t* __restrict__ runs, const int* __restrict__ cnt,
                        int* __restrict__ parent){
  int t = blockIdx.x*blockDim.x + threadIdx.x;
  int bi = t >> 3, k0 = t & 7;
  if (bi >= BB*NBND) return;
  int img = bi / NBND, j = bi % NBND;
  int r = img*HH + (j + 1)*ORPB;              // top row of slab; link to r-1
  int ca = cnt[r];
  int cb = cnt[r-1];
  if (cb == 0) return;
  const uint32_t* RB = runs + (size_t)(r-1)*RS;
  for (int k = k0; k < ca; k += 8){
    int id = r*RS + k;
    uint32_t ra = runs[id]; int sA = (int)(ra & 0xffff), eA = (int)(ra >> 16);
    int lo = 0, hi = cb, target = sA - 1;
    while (lo < hi){
      int mid = (lo + hi) >> 1;
      if ((int)(RB[mid] >> 16) < target) lo = mid + 1; else hi = mid;
    }
    for (int jj = lo; jj < cb; ++jj){
      uint32_t rb = RB[jj];
      if ((int)(rb & 0xffff) > eA + 1) break;
      uf_union(parent, id, (r-1)*RS + jj);
    }
  }
}

// ---------------- slab accumulate: direct LDS index, no hash --------------
__global__ __launch_bounds__(256)
void k_slabacc(const uint32_t* __restrict__ runs, const int* __restrict__ cnt,
               int* __restrict__ parent, int* __restrict__ area,
               int* __restrict__ clabel){
  __shared__ int larea[SLABN];
  __shared__ int lclab[SLABN];
  for (int i = threadIdx.x; i < SLABN; i += 256){ larea[i] = 0; lclab[i] = 0; }
  __syncthreads();
  int R0 = blockIdx.x * ORPB;
  int base = R0 * RS;
  int y0 = R0 & (HH - 1);
  int ri = threadIdx.x / TPR;          // 0..ORPB-1
  int k0 = threadIdx.x % TPR;
  int r = R0 + ri;
  int n = cnt[r];
  for (int k = k0; k < n; k += TPR){
    int id = r*RS + k;
    uint32_t run = runs[id]; int s = (int)(run & 0xffff), e = (int)(run >> 16);
    int len = e - s + 1;
    int labl = ri*WW + e + 1;          // local label; +y0*WW at flush
    int p = parent[id];
    int lid = p - base;
    if ((unsigned)lid < (unsigned)SLABN){
      atomicAdd(&larea[lid], len);     // LDS atomics, CU-local
      atomicMax(&lclab[lid], labl);
    } else {
      p = ro_find(parent, p);
      atomicAdd(&area[p], len);
      atomicMax(&clabel[p], y0*WW + labl);
    }
  }
  __syncthreads();
  // flush: one global atomic pair per contributing slot
  for (int i = threadIdx.x; i < SLABN; i += 256){
    int la = larea[i];
    if (la == 0) continue;
    int gid = base + i;
    int p = ro_find(parent, gid);
    atomicAdd(&area[p], la);
    atomicMax(&clabel[p], y0*WW + lclab[i]);
    if (p != gid) parent[gid] = p;     // shortcut to final root (monotone)
  }
}

// ---------------- compact roots per image ----------------
__global__ void k_roots(const int* __restrict__ cnt, const int* __restrict__ parent,
                        const int* __restrict__ area, const int* __restrict__ clabel,
                        int* __restrict__ rootcnt, int* __restrict__ rootA,
                        int* __restrict__ rootL){
  int t = blockIdx.x*blockDim.x + threadIdx.x;
  if (t >= NROWS*KPR) return;
  int r = t / KPR, k0 = t % KPR;
  int n = cnt[r];
  int b = r >> 9;
  for (int k = k0; k < n; k += KPR){
    int id = r*RS + k;
    if (parent[id] != id) continue;          // global roots only
    int a = area[id];
    if (a < 200) continue;                   // MIN_AREA
    int idx = atomicAdd(&rootcnt[b], 1);
    rootA[b*MAXROOTS + idx] = a;
    rootL[b*MAXROOTS + idx] = clabel[id];
  }
}

// ---------------- top-2 per image (area desc, label asc tie) --------------
__device__ __forceinline__ void ins2(int v, int i, int& v1, int& i1, int& v2, int& i2){
  if (v > v1 || (v == v1 && i < i1)) { v2 = v1; i2 = i1; v1 = v; i1 = i; }
  else if (v > v2 || (v == v2 && i < i2)) { v2 = v; i2 = i; }
}

__global__ void k_top2(const int* __restrict__ rootcnt, const int* __restrict__ rootA,
                       const int* __restrict__ rootL, int* __restrict__ keepL){
  __shared__ int sv1[64], si1[64], sv2[64], si2[64];
  int b = blockIdx.x;
  int n = rootcnt[b];
  int v1 = 0, i1 = INT_MAX, v2 = 0, i2 = INT_MAX;
  for (int k = threadIdx.x; k < n; k += 64)
    ins2(rootA[b*MAXROOTS + k], rootL[b*MAXROOTS + k], v1, i1, v2, i2);
  int t = threadIdx.x;
  sv1[t] = v1; si1[t] = i1; sv2[t] = v2; si2[t] = i2;
  __syncthreads();
  for (int s = 32; s > 0; s >>= 1){
    if (t < s){
      int a1 = sv1[t], b1 = si1[t], a2 = sv2[t], b2 = si2[t];
      ins2(sv1[t+s], si1[t+s], a1, b1, a2, b2);
      ins2(sv2[t+s], si2[t+s], a1, b1, a2, b2);
      sv1[t] = a1; si1[t] = b1; sv2[t] = a2; si2[t] = b2;
    }
    __syncthreads();
  }
  if (t == 0){
    keepL[b*2 + 0] = (sv1[0] > 0) ? si1[0] : 0;   // 0 invalid (labels >= 1)
    keepL[b*2 + 1] = (sv2[0] > 0) ? si2[0] : 0;
  }
}

// ---------------- fused keep-build + close (dilate5+erode5) + expand ------
__device__ __forceinline__ u64 rmask(int s, int e){  // bits s..e inclusive
  u64 hi = (e >= 63) ? ~0ULL : ((1ULL << (e + 1)) - 1);
  u64 lo = (1ULL << s) - 1;
  return hi & ~lo;
}

#define CRPB 16                // 2048 blocks -> 32 waves/CU grid cap
__global__ __launch_bounds__(256)
void k_closeexpand(const uint32_t* __restrict__ runs, const int* __restrict__ cnt,
                   const int* __restrict__ parent, const int* __restrict__ clabel,
                   const int* __restrict__ keepL, float* __restrict__ out){
  __shared__ u64 kp[CRPB + 8][WPR];   // keep rows y0-4 .. y0+19
  __shared__ u64 dil[CRPB + 4][WPR];  // dilated rows y0-2 .. y0+17
  __shared__ u64 ero[CRPB][WPR];
  __shared__ int scnt[CRPB + 8];
  int R0 = blockIdx.x * CRPB;
  int img = R0 >> 9;
  int y0 = R0 & (HH - 1);
  int L1 = keepL[img*2], L2 = keepL[img*2 + 1];
  // phase 0a: zero kp + stage per-row counts
  for (int i = threadIdx.x; i < (CRPB + 8)*WPR; i += 256)
    kp[i >> 3][i & 7] = 0ULL;
  if (threadIdx.x < CRPB + 8){
    int y = y0 + threadIdx.x - 4;
    scnt[threadIdx.x] = ((unsigned)y < (unsigned)HH) ? cnt[img*HH + y] : 0;
  }
  __syncthreads();
  // phase 0b: build keep bits, 8 threads per row; LDS atomicOr commit
  for (int rr = threadIdx.x >> 3; rr < CRPB + 8; rr += 32){
    int y = y0 + rr - 4;
    int row = img*HH + y;
    int n = scnt[rr];
    for (int k = threadIdx.x & 7; k < n; k += 8){
      int id = row*RS + k;
      int p = parent[id];
      while (true){ int q = parent[p]; if (q == p) break; p = q; }  // depth<=3
      int L = clabel[p];
      if (L != L1 && L != L2) continue;
      uint32_t run = runs[id]; int st = (int)(run & 0xffff), e = (int)(run >> 16);
      int w0 = st >> 6, w1 = e >> 6;
      if (w0 == w1) atomicOr(&kp[rr][w0], rmask(st & 63, e & 63));
      else {
        atomicOr(&kp[rr][w0], rmask(st & 63, 63));
        for (int wi = w0 + 1; wi < w1; ++wi) atomicOr(&kp[rr][wi], ~0ULL);
        atomicOr(&kp[rr][w1], rmask(0, e & 63));
      }
    }
  }
  __syncthreads();
  // phase 1: dilate5 rows y0-2 .. y0+CRPB+1
  for (int s = threadIdx.x; s < (CRPB + 4)*WPR; s += 256){
    int li = s >> 3;
    int wi = s & 7;
    u64 acc = 0ULL;
    #pragma unroll
    for (int dy = -2; dy <= 2; ++dy){
      int ki = li + 2 + dy;
      u64 c = kp[ki][wi];
      u64 l = (wi > 0) ? kp[ki][wi-1] : 0ULL;
      u64 r = (wi < 7) ? kp[ki][wi+1] : 0ULL;
      acc |= hshift5_or(c, l, r);
    }
    dil[li][wi] = acc;
  }
  __syncthreads();
  // phase 2: erode5 center rows (zero pad outside image)
  for (int s = threadIdx.x; s < CRPB*WPR; s += 256){
    int ri = s >> 3;
    int wi = s & 7;
    int y = y0 + ri;
    u64 acc = ~0ULL;
    #pragma unroll
    for (int dy = -2; dy <= 2; ++dy){
      int yy = y + dy;
      u64 h;
      if ((unsigned)yy >= (unsigned)HH) h = 0ULL;
      else {
        int li = ri + 2 + dy;
        u64 c = dil[li][wi];
        u64 l = (wi > 0) ? dil[li][wi-1] : 0ULL;
        u64 r = (wi < 7) ? dil[li][wi+1] : 0ULL;
        h = hshift5_and(c, l, r);
      }
      acc &= h;
    }
    ero[ri][wi] = acc;
  }
  __syncthreads();
  // phase 3: expand to f32, coalesced float4 stores
  float4* O = reinterpret_cast<float4*>(out + (size_t)R0*WW);
  for (int i = threadIdx.x; i < CRPB*WW/4; i += 256){
    int px = i * 4;
    int row = px >> 9;
    int x = px & (WW - 1);
    u64 word = ero[row][x >> 6];
    unsigned nib = (unsigned)((word >> (x & 63)) & 0xFULL);
    float4 f;
    f.x = (float)( nib       & 1);
    f.y = (float)((nib >> 1) & 1);
    f.z = (float)((nib >> 2) & 1);
    f.w = (float)((nib >> 3) & 1);
    O[i] = f;
  }
}

// ---------------- launch ----------------
extern "C" void kernel_launch(void* const* d_in, const int* in_sizes, int n_in,
                              void* d_out, int out_size, void* d_ws, size_t ws_size,
                              hipStream_t stream){
  const float* x = (const float*)d_in[0];
  float* out = (float*)d_out;
  char* ws = (char*)d_ws;

  const size_t BITS_OFF    = 0;                         // 2 MiB (thresh bitmap)
  const size_t RUNS_OFF    = BITS_OFF   + 2097152ull;   // 16 MiB
  const size_t PAR_OFF     = RUNS_OFF   + (size_t)MAXRUNS*4;
  const size_t AREA_OFF    = PAR_OFF    + (size_t)MAXRUNS*4;
  const size_t CLAB_OFF    = AREA_OFF   + (size_t)MAXRUNS*4;
  const size_t CNT_OFF     = CLAB_OFF   + (size_t)MAXRUNS*4;
  const size_t RCNT_OFF    = CNT_OFF    + (size_t)NROWS*4;
  const size_t RA_OFF      = RCNT_OFF   + 1024ull;
  const size_t RL_OFF      = RA_OFF     + (size_t)BB*MAXROOTS*4;
  const size_t KEEPL_OFF   = RL_OFF     + (size_t)BB*MAXROOTS*4;

  u64*      bits     = (u64*)(ws + BITS_OFF);
  uint32_t* runs     = (uint32_t*)(ws + RUNS_OFF);
  int*      parent   = (int*)(ws + PAR_OFF);
  int*      area     = (int*)(ws + AREA_OFF);
  int*      clabel   = (int*)(ws + CLAB_OFF);
  int*      cnt      = (int*)(ws + CNT_OFF);
  int*      rootcnt  = (int*)(ws + RCNT_OFF);
  int*      rootA    = (int*)(ws + RA_OFF);
  int*      rootL    = (int*)(ws + RL_OFF);
  int*      keepL    = (int*)(ws + KEEPL_OFF);

  const int T = 256;
  dim3 blk(T);

  // 1) threshold+pack (full-occupancy stream; zeroes rootcnt)
  k_threshpack<<<dim3(NPIX/16/T), blk, 0, stream>>>(x, bits, rootcnt);
  // 2) open + runs + slab-local UF (reads 2 MB bitmap from L2)
  k_openlocal<<<dim3(NROWS/ORPB), blk, 0, stream>>>(bits, runs, cnt, parent,
                                                    area, clabel);
  // 3) boundary link (1984 seam rows)
  k_linkb<<<dim3((BB*NBND*8 + T - 1)/T), blk, 0, stream>>>(runs, cnt, parent);
  // 4) slab accumulate (direct LDS index)
  k_slabacc<<<dim3(NROWS/ORPB), blk, 0, stream>>>(runs, cnt, parent, area, clabel);
  // 5) compact roots
  k_roots<<<dim3(NROWS*KPR/T), blk, 0, stream>>>(cnt, parent, area, clabel,
                                                 rootcnt, rootA, rootL);
  // 6) top-2 per image over compacted candidates
  k_top2<<<dim3(BB), dim3(64), 0, stream>>>(rootcnt, rootA, rootL, keepL);
  // 7) fused keep-build + close + expand -> f32 out (2048 blocks)
  k_closeexpand<<<dim3(NROWS/CRPB), blk, 0, stream>>>(runs, cnt, parent, clabel,
                                                      keepL, out);

  (void)in_sizes; (void)n_in; (void)out_size; (void)ws_size;
}

// Round 21
// 94.918 us; speedup vs baseline: 1.0427x; 1.0427x over previous
//
#include <hip/hip_runtime.h>
#include <stdint.h>
#include <limits.h>

#define BB 64
#define HH 512
#define WW 512
#define WPR 8                  // 64-bit words per row
#define WPRP 9                 // padded LDS stride
#define HWP (HH*WW)            // 262144
#define NPIX (BB*HWP)          // 16777216
#define NROWS (BB*HH)          // 32768
#define RS 128                 // exact max runs/row in opened mask (len>=3, gap>=1)
#define RSP 129                // padded LDS run stride
#define MAXRUNS (NROWS*RS)     // 4194304
#define KPR 32                 // roots threads per row
#define MAXROOTS 2048          // area>=200 roots per image <= 1310

typedef unsigned char u8;
typedef unsigned long long u64;

__device__ __forceinline__ int imax(int a, int b){ return a > b ? a : b; }

// ---------------- helpers for bit morphology ----------------
__device__ __forceinline__ u64 hshift3_and(u64 c, u64 l, u64 r){
  return c & ((c << 1) | (l >> 63)) & ((c >> 1) | (r << 63));
}
__device__ __forceinline__ u64 hshift3_or(u64 c, u64 l, u64 r){
  return c | (c << 1) | (l >> 63) | (c >> 1) | (r << 63);
}
__device__ __forceinline__ u64 hshift5_and(u64 c, u64 l, u64 r){
  return hshift3_and(c, l, r) & ((c << 2) | (l >> 62)) & ((c >> 2) | (r << 62));
}
__device__ __forceinline__ u64 hshift5_or(u64 c, u64 l, u64 r){
  return hshift3_or(c, l, r) | (c << 2) | (l >> 62) | (c >> 2) | (r << 62);
}

// ---------------- LDS union-find (slab-local, path halving) ---------------
__device__ __forceinline__ int lfind(int* lp, int p){
  while (true){
    int q = lp[p];
    int g = lp[q];
    if (q == g) return q;
    atomicMin(&lp[p], g);
    p = g;
  }
}
__device__ __forceinline__ void lunion(int* lp, int a, int b){
  while (true){
    a = lfind(lp, a);
    b = lfind(lp, b);
    if (a == b) return;
    if (a < b){ int t = a; a = b; b = t; }
    int old = atomicMin(&lp[a], b);
    if (old == a) return;
    a = old;
  }
}

// ------- fused threshold + open (erode3+dilate3) + runs + slab-local UF ---
// dl aliases thr (dead after phase E) -> LDS ~19.3 KB
#define ORPB 16
#define TPR (256/ORPB)         // 16 threads per row in L/W phases
#define SLABN (ORPB*RS)        // 2048 run slots per slab
__global__ __launch_bounds__(256)
void k_thropen(const float* __restrict__ x, uint32_t* __restrict__ runs,
               int* __restrict__ cnt, int* __restrict__ parent,
               int* __restrict__ area, int* __restrict__ clabel,
               int* __restrict__ rootcnt){
  __shared__ u64 thr[ORPB + 4][WPRP];  // phase T: thresh rows; phase D+: dl rows
  __shared__ u64 er[ORPB + 2][WPRP];   // y0-1 .. y0+16
  __shared__ uint32_t lruns[ORPB][RSP];
  __shared__ int lcnt[ORPB];
  __shared__ int lparent[SLABN];
  int R0 = blockIdx.x * ORPB;
  int img = R0 >> 9;
  int y0 = R0 & (HH - 1);
  int wid  = threadIdx.x >> 6;
  int lane = threadIdx.x & 63;
  if (blockIdx.x == 0 && threadIdx.x < BB) rootcnt[threadIdx.x] = 0;

  // phase T: (ORPB+4)/2 = 10 row-pairs over 4 waves (ballot-pack)
  for (int pair = wid; pair < (ORPB + 4)/2; pair += 4){
    int lrow = 2*pair + (lane >> 5);          // LDS row 0..19
    int y = y0 - 2 + lrow;                    // image row
    unsigned m = 0;
    if ((unsigned)y < (unsigned)HH){
      const float4* X = reinterpret_cast<const float4*>(
          x + ((size_t)img*HH + y)*WW + (lane & 31)*16);
      #pragma unroll
      for (int q = 0; q < 4; ++q){
        float4 vv = X[q];
        m |= (unsigned)(vv.x > -0.5f) << (q*4 + 0);
        m |= (unsigned)(vv.y > -0.5f) << (q*4 + 1);
        m |= (unsigned)(vv.z > -0.5f) << (q*4 + 2);
        m |= (unsigned)(vv.w > -0.5f) << (q*4 + 3);
      }
    }
    int sub = lane & 3;
    unsigned p1 = __shfl_xor(m, 1);
    unsigned v32 = (sub & 1) ? (p1 | (m << 16)) : (m | (p1 << 16));
    unsigned p2 = __shfl_xor(v32, 2);
    if (sub == 0)
      thr[lrow][(lane >> 2) & 7] = (u64)v32 | ((u64)p2 << 32);
  }
  __syncthreads();

  // phase E: erode3x3 -> er rows j (image row y0-1+j)
  for (int s = threadIdx.x; s < (ORPB + 2)*WPR; s += 256){
    int j = s >> 3;
    int wi = s & 7;
    int rr = y0 - 1 + j;
    u64 acc = ~0ULL;
    #pragma unroll
    for (int dy = 0; dy < 3; ++dy){
      int ti = j + dy;
      u64 c = thr[ti][wi];
      u64 l = (wi > 0) ? thr[ti][wi-1] : 0ULL;
      u64 r = (wi < 7) ? thr[ti][wi+1] : 0ULL;
      acc &= hshift3_and(c, l, r);
    }
    if ((unsigned)rr >= (unsigned)HH) acc = 0ULL;
    er[j][wi] = acc;
  }
  __syncthreads();

  // phase D: dilate3x3 -> thr[ri] (thr dead after E; aliasing saves LDS)
  for (int s = threadIdx.x; s < ORPB*WPR; s += 256){
    int ri = s >> 3;
    int wi = s & 7;
    u64 acc = 0ULL;
    #pragma unroll
    for (int dy = 0; dy < 3; ++dy){
      int li = ri + dy;
      u64 c = er[li][wi];
      u64 l = (wi > 0) ? er[li][wi-1] : 0ULL;
      u64 r = (wi < 7) ? er[li][wi+1] : 0ULL;
      acc |= hshift3_or(c, l, r);
    }
    thr[ri][wi] = acc;
  }
  __syncthreads();

  // init local parent (identity)
  for (int i = threadIdx.x; i < SLABN; i += 256) lparent[i] = i;

  // phase R: run extraction, one thread per row (reads dl from thr)
  if (threadIdx.x < ORPB){
    int ri = threadIdx.x;
    int r = R0 + ri;
    u64 w[8];
    #pragma unroll
    for (int i = 0; i < 8; ++i) w[i] = thr[ri][i];
    int base = r*RS;
    int k = 0;
    int pending = -1;
    u64 carry = 0;
    #pragma unroll
    for (int wi = 0; wi < 8; ++wi){
      u64 b = w[wi];
      u64 nb0 = (wi < 7) ? (w[wi+1] & 1ULL) : 0ULL;
      u64 starts = b & ~((b << 1) | carry);
      u64 ends   = b & ~(b >> 1);
      if (nb0) ends &= ~(1ULL << 63);
      carry = b >> 63;
      while (ends){
        int e = __ffsll((long long)ends) - 1; ends &= ends - 1;
        int s;
        if (pending >= 0){ s = pending; pending = -1; }
        else { s = wi*64 + (__ffsll((long long)starts) - 1); starts &= starts - 1; }
        uint32_t rv = (uint32_t)s | ((uint32_t)(wi*64 + e) << 16);
        int id = base + k;
        runs[id] = rv; lruns[ri][k] = rv;
        area[id] = 0; clabel[id] = 0;
        k++;
      }
      if (starts) pending = wi*64 + (__ffsll((long long)starts) - 1);
    }
    cnt[r] = k; lcnt[ri] = k;
  }
  __syncthreads();

  // phase L: local link rows 1..ORPB-1 (TPR threads per row)
  {
    int ri = threadIdx.x / TPR;
    int k0 = threadIdx.x % TPR;
    if (ri > 0){
      int ca = lcnt[ri], cb = lcnt[ri-1];
      if (cb > 0){
        for (int k = k0; k < ca; k += TPR){
          uint32_t ra = lruns[ri][k]; int sA = (int)(ra & 0xffff), eA = (int)(ra >> 16);
          int lo = 0, hi = cb, target = sA - 1;
          while (lo < hi){
            int mid = (lo + hi) >> 1;
            if ((int)(lruns[ri-1][mid] >> 16) < target) lo = mid + 1; else hi = mid;
          }
          for (int j = lo; j < cb; ++j){
            if ((int)(lruns[ri-1][j] & 0xffff) > eA + 1) break;
            lunion(lparent, ri*RS + k, (ri-1)*RS + j);
          }
        }
      }
    }
  }
  __syncthreads();

  // phase W: write global parent = slab root (global id space)
  {
    int ri = threadIdx.x / TPR;
    int k0 = threadIdx.x % TPR;
    int n = lcnt[ri];
    for (int k = k0; k < n; k += TPR){
      int lid = ri*RS + k;
      parent[R0*RS + lid] = R0*RS + lfind(lparent, lid);
    }
  }
}

// ---------------- global union-find (path halving) ----------------
__device__ __forceinline__ int uf_find(int* parent, int p){
  while (true){
    int q = parent[p];
    int g = parent[q];
    if (q == g) return q;
    atomicMin(&parent[p], g);
    p = g;
  }
}
__device__ __forceinline__ void uf_union(int* parent, int a, int b){
  while (true){
    a = uf_find(parent, a);
    b = uf_find(parent, b);
    if (a == b) return;
    if (a < b){ int t = a; a = b; b = t; }
    int old = atomicMin(&parent[a], b);
    if (old == a) return;
    a = old;
  }
}

// read-only find
__device__ __forceinline__ int ro_find(const int* __restrict__ parent, int p){
  while (true){ int q = parent[p]; if (q == p) return p; p = q; }
}

// ---------------- boundary link: only rows at slab seams ------------------
#define NBND (HH/ORPB - 1)     // 31 per image
__global__ void k_linkb(const uint32_t* __restrict__ runs, const int* __restrict__ cnt,
                        int* __restrict__ parent){
  int t = blockIdx.x*blockDim.x + threadIdx.x;
  int bi = t >> 3, k0 = t & 7;
  if (bi >= BB*NBND) return;
  int img = bi / NBND, j = bi % NBND;
  int r = img*HH + (j + 1)*ORPB;              // top row of slab; link to r-1
  int ca = cnt[r];
  int cb = cnt[r-1];
  if (cb == 0) return;
  const uint32_t* RB = runs + (size_t)(r-1)*RS;
  for (int k = k0; k < ca; k += 8){
    int id = r*RS + k;
    uint32_t ra = runs[id]; int sA = (int)(ra & 0xffff), eA = (int)(ra >> 16);
    int lo = 0, hi = cb, target = sA - 1;
    while (lo < hi){
      int mid = (lo + hi) >> 1;
      if ((int)(RB[mid] >> 16) < target) lo = mid + 1; else hi = mid;
    }
    for (int jj = lo; jj < cb; ++jj){
      uint32_t rb = RB[jj];
      if ((int)(rb & 0xffff) > eA + 1) break;
      uf_union(parent, id, (r-1)*RS + jj);
    }
  }
}

// ---------------- slab accumulate: direct LDS index, no hash --------------
__global__ __launch_bounds__(256)
void k_slabacc(const uint32_t* __restrict__ runs, const int* __restrict__ cnt,
               int* __restrict__ parent, int* __restrict__ area,
               int* __restrict__ clabel){
  __shared__ int larea[SLABN];
  __shared__ int lclab[SLABN];
  for (int i = threadIdx.x; i < SLABN; i += 256){ larea[i] = 0; lclab[i] = 0; }
  __syncthreads();
  int R0 = blockIdx.x * ORPB;
  int base = R0 * RS;
  int y0 = R0 & (HH - 1);
  int ri = threadIdx.x / TPR;          // 0..ORPB-1
  int k0 = threadIdx.x % TPR;
  int r = R0 + ri;
  int n = cnt[r];
  for (int k = k0; k < n; k += TPR){
    int id = r*RS + k;
    uint32_t run = runs[id]; int s = (int)(run & 0xffff), e = (int)(run >> 16);
    int len = e - s + 1;
    int labl = ri*WW + e + 1;          // local label; +y0*WW at flush
    int p = parent[id];
    int lid = p - base;
    if ((unsigned)lid < (unsigned)SLABN){
      atomicAdd(&larea[lid], len);     // LDS atomics, CU-local
      atomicMax(&lclab[lid], labl);
    } else {
      p = ro_find(parent, p);
      atomicAdd(&area[p], len);
      atomicMax(&clabel[p], y0*WW + labl);
    }
  }
  __syncthreads();
  // flush: one global atomic pair per contributing slot
  for (int i = threadIdx.x; i < SLABN; i += 256){
    int la = larea[i];
    if (la == 0) continue;
    int gid = base + i;
    int p = ro_find(parent, gid);
    atomicAdd(&area[p], la);
    atomicMax(&clabel[p], y0*WW + lclab[i]);
    if (p != gid) parent[gid] = p;     // shortcut to final root (monotone)
  }
}

// ---------------- compact roots per image ----------------
__global__ void k_roots(const int* __restrict__ cnt, const int* __restrict__ parent,
                        const int* __restrict__ area, const int* __restrict__ clabel,
                        int* __restrict__ rootcnt, int* __restrict__ rootA,
                        int* __restrict__ rootL){
  int t = blockIdx.x*blockDim.x + threadIdx.x;
  if (t >= NROWS*KPR) return;
  int r = t / KPR, k0 = t % KPR;
  int n = cnt[r];
  int b = r >> 9;
  for (int k = k0; k < n; k += KPR){
    int id = r*RS + k;
    if (parent[id] != id) continue;          // global roots only
    int a = area[id];
    if (a < 200) continue;                   // MIN_AREA
    int idx = atomicAdd(&rootcnt[b], 1);
    rootA[b*MAXROOTS + idx] = a;
    rootL[b*MAXROOTS + idx] = clabel[id];
  }
}

// ---------------- top-2 per image (area desc, label asc tie) --------------
__device__ __forceinline__ void ins2(int v, int i, int& v1, int& i1, int& v2, int& i2){
  if (v > v1 || (v == v1 && i < i1)) { v2 = v1; i2 = i1; v1 = v; i1 = i; }
  else if (v > v2 || (v == v2 && i < i2)) { v2 = v; i2 = i; }
}

__global__ void k_top2(const int* __restrict__ rootcnt, const int* __restrict__ rootA,
                       const int* __restrict__ rootL, int* __restrict__ keepL){
  __shared__ int sv1[64], si1[64], sv2[64], si2[64];
  int b = blockIdx.x;
  int n = rootcnt[b];
  int v1 = 0, i1 = INT_MAX, v2 = 0, i2 = INT_MAX;
  for (int k = threadIdx.x; k < n; k += 64)
    ins2(rootA[b*MAXROOTS + k], rootL[b*MAXROOTS + k], v1, i1, v2, i2);
  int t = threadIdx.x;
  sv1[t] = v1; si1[t] = i1; sv2[t] = v2; si2[t] = i2;
  __syncthreads();
  for (int s = 32; s > 0; s >>= 1){
    if (t < s){
      int a1 = sv1[t], b1 = si1[t], a2 = sv2[t], b2 = si2[t];
      ins2(sv1[t+s], si1[t+s], a1, b1, a2, b2);
      ins2(sv2[t+s], si2[t+s], a1, b1, a2, b2);
      sv1[t] = a1; si1[t] = b1; sv2[t] = a2; si2[t] = b2;
    }
    __syncthreads();
  }
  if (t == 0){
    keepL[b*2 + 0] = (sv1[0] > 0) ? si1[0] : 0;   // 0 invalid (labels >= 1)
    keepL[b*2 + 1] = (sv2[0] > 0) ? si2[0] : 0;
  }
}

// ---------------- fused keep-build + close (dilate5+erode5) + expand ------
__device__ __forceinline__ u64 rmask(int s, int e){  // bits s..e inclusive
  u64 hi = (e >= 63) ? ~0ULL : ((1ULL << (e + 1)) - 1);
  u64 lo = (1ULL << s) - 1;
  return hi & ~lo;
}

#define CRPB 16                // 2048 blocks -> 32 waves/CU grid cap
__global__ __launch_bounds__(256)
void k_closeexpand(const uint32_t* __restrict__ runs, const int* __restrict__ cnt,
                   const int* __restrict__ parent, const int* __restrict__ clabel,
                   const int* __restrict__ keepL, float* __restrict__ out){
  __shared__ u64 kp[CRPB + 8][WPR];   // keep rows y0-4 .. y0+19
  __shared__ u64 dil[CRPB + 4][WPR];  // dilated rows y0-2 .. y0+17
  __shared__ u64 ero[CRPB][WPR];
  __shared__ int scnt[CRPB + 8];
  int R0 = blockIdx.x * CRPB;
  int img = R0 >> 9;
  int y0 = R0 & (HH - 1);
  int L1 = keepL[img*2], L2 = keepL[img*2 + 1];
  // phase 0a: zero kp + stage per-row counts
  for (int i = threadIdx.x; i < (CRPB + 8)*WPR; i += 256)
    kp[i >> 3][i & 7] = 0ULL;
  if (threadIdx.x < CRPB + 8){
    int y = y0 + threadIdx.x - 4;
    scnt[threadIdx.x] = ((unsigned)y < (unsigned)HH) ? cnt[img*HH + y] : 0;
  }
  __syncthreads();
  // phase 0b: build keep bits, 8 threads per row; LDS atomicOr commit
  for (int rr = threadIdx.x >> 3; rr < CRPB + 8; rr += 32){
    int y = y0 + rr - 4;
    int row = img*HH + y;
    int n = scnt[rr];
    for (int k = threadIdx.x & 7; k < n; k += 8){
      int id = row*RS + k;
      int p = parent[id];
      while (true){ int q = parent[p]; if (q == p) break; p = q; }  // depth<=3
      int L = clabel[p];
      if (L != L1 && L != L2) continue;
      uint32_t run = runs[id]; int st = (int)(run & 0xffff), e = (int)(run >> 16);
      int w0 = st >> 6, w1 = e >> 6;
      if (w0 == w1) atomicOr(&kp[rr][w0], rmask(st & 63, e & 63));
      else {
        atomicOr(&kp[rr][w0], rmask(st & 63, 63));
        for (int wi = w0 + 1; wi < w1; ++wi) atomicOr(&kp[rr][wi], ~0ULL);
        atomicOr(&kp[rr][w1], rmask(0, e & 63));
      }
    }
  }
  __syncthreads();
  // phase 1: dilate5 rows y0-2 .. y0+CRPB+1
  for (int s = threadIdx.x; s < (CRPB + 4)*WPR; s += 256){
    int li = s >> 3;
    int wi = s & 7;
    u64 acc = 0ULL;
    #pragma unroll
    for (int dy = -2; dy <= 2; ++dy){
      int ki = li + 2 + dy;
      u64 c = kp[ki][wi];
      u64 l = (wi > 0) ? kp[ki][wi-1] : 0ULL;
      u64 r = (wi < 7) ? kp[ki][wi+1] : 0ULL;
      acc |= hshift5_or(c, l, r);
    }
    dil[li][wi] = acc;
  }
  __syncthreads();
  // phase 2: erode5 center rows (zero pad outside image)
  for (int s = threadIdx.x; s < CRPB*WPR; s += 256){
    int ri = s >> 3;
    int wi = s & 7;
    int y = y0 + ri;
    u64 acc = ~0ULL;
    #pragma unroll
    for (int dy = -2; dy <= 2; ++dy){
      int yy = y + dy;
      u64 h;
      if ((unsigned)yy >= (unsigned)HH) h = 0ULL;
      else {
        int li = ri + 2 + dy;
        u64 c = dil[li][wi];
        u64 l = (wi > 0) ? dil[li][wi-1] : 0ULL;
        u64 r = (wi < 7) ? dil[li][wi+1] : 0ULL;
        h = hshift5_and(c, l, r);
      }
      acc &= h;
    }
    ero[ri][wi] = acc;
  }
  __syncthreads();
  // phase 3: expand to f32, coalesced float4 stores
  float4* O = reinterpret_cast<float4*>(out + (size_t)R0*WW);
  for (int i = threadIdx.x; i < CRPB*WW/4; i += 256){
    int px = i * 4;
    int row = px >> 9;
    int x = px & (WW - 1);
    u64 word = ero[row][x >> 6];
    unsigned nib = (unsigned)((word >> (x & 63)) & 0xFULL);
    float4 f;
    f.x = (float)( nib       & 1);
    f.y = (float)((nib >> 1) & 1);
    f.z = (float)((nib >> 2) & 1);
    f.w = (float)((nib >> 3) & 1);
    O[i] = f;
  }
}

// ---------------- launch ----------------
extern "C" void kernel_launch(void* const* d_in, const int* in_sizes, int n_in,
                              void* d_out, int out_size, void* d_ws, size_t ws_size,
                              hipStream_t stream){
  const float* x = (const float*)d_in[0];
  float* out = (float*)d_out;
  char* ws = (char*)d_ws;

  const size_t RUNS_OFF    = 0;                         // 16 MiB
  const size_t PAR_OFF     = RUNS_OFF   + (size_t)MAXRUNS*4;
  const size_t AREA_OFF    = PAR_OFF    + (size_t)MAXRUNS*4;
  const size_t CLAB_OFF    = AREA_OFF   + (size_t)MAXRUNS*4;
  const size_t CNT_OFF     = CLAB_OFF   + (size_t)MAXRUNS*4;
  const size_t RCNT_OFF    = CNT_OFF    + (size_t)NROWS*4;
  const size_t RA_OFF      = RCNT_OFF   + 1024ull;
  const size_t RL_OFF      = RA_OFF     + (size_t)BB*MAXROOTS*4;
  const size_t KEEPL_OFF   = RL_OFF     + (size_t)BB*MAXROOTS*4;

  uint32_t* runs     = (uint32_t*)(ws + RUNS_OFF);
  int*      parent   = (int*)(ws + PAR_OFF);
  int*      area     = (int*)(ws + AREA_OFF);
  int*      clabel   = (int*)(ws + CLAB_OFF);
  int*      cnt      = (int*)(ws + CNT_OFF);
  int*      rootcnt  = (int*)(ws + RCNT_OFF);
  int*      rootA    = (int*)(ws + RA_OFF);
  int*      rootL    = (int*)(ws + RL_OFF);
  int*      keepL    = (int*)(ws + KEEPL_OFF);

  const int T = 256;
  dim3 blk(T);

  // 1) fused threshold + open + runs + slab-local UF (2048 blocks, 8/CU)
  k_thropen<<<dim3(NROWS/ORPB), blk, 0, stream>>>(x, runs, cnt, parent, area,
                                                  clabel, rootcnt);
  // 2) boundary link (1984 seam rows)
  k_linkb<<<dim3((BB*NBND*8 + T - 1)/T), blk, 0, stream>>>(runs, cnt, parent);
  // 3) slab accumulate (direct LDS index)
  k_slabacc<<<dim3(NROWS/ORPB), blk, 0, stream>>>(runs, cnt, parent, area, clabel);
  // 4) compact roots
  k_roots<<<dim3(NROWS*KPR/T), blk, 0, stream>>>(cnt, parent, area, clabel,
                                                 rootcnt, rootA, rootL);
  // 5) top-2 per image over compacted candidates
  k_top2<<<dim3(BB), dim3(64), 0, stream>>>(rootcnt, rootA, rootL, keepL);
  // 6) fused keep-build + close + expand -> f32 out (2048 blocks)
  k_closeexpand<<<dim3(NROWS/CRPB), blk, 0, stream>>>(runs, cnt, parent, clabel,
                                                      keepL, out);

  (void)in_sizes; (void)n_in; (void)out_size; (void)ws_size;
}

// Round 22
// 91.104 us; speedup vs baseline: 1.0864x; 1.0419x over previous
//
#include <hip/hip_runtime.h>
#include <stdint.h>
#include <limits.h>

#define BB 64
#define HH 512
#define WW 512
#define WPR 8                  // 64-bit words per row
#define WPRP 9                 // padded LDS stride
#define HWP (HH*WW)            // 262144
#define NPIX (BB*HWP)          // 16777216
#define NROWS (BB*HH)          // 32768
#define RS 128                 // exact max runs/row in opened mask (len>=3, gap>=1)
#define RSP 129                // padded LDS run stride
#define MAXRUNS (NROWS*RS)     // 4194304
#define KPR 32                 // roots threads per row
#define MAXROOTS 2048          // area>=200 roots per image <= 1310

typedef unsigned char u8;
typedef unsigned long long u64;

__device__ __forceinline__ int imax(int a, int b){ return a > b ? a : b; }

// ---------------- helpers for bit morphology ----------------
__device__ __forceinline__ u64 hshift3_and(u64 c, u64 l, u64 r){
  return c & ((c << 1) | (l >> 63)) & ((c >> 1) | (r << 63));
}
__device__ __forceinline__ u64 hshift3_or(u64 c, u64 l, u64 r){
  return c | (c << 1) | (l >> 63) | (c >> 1) | (r << 63);
}
__device__ __forceinline__ u64 hshift5_and(u64 c, u64 l, u64 r){
  return hshift3_and(c, l, r) & ((c << 2) | (l >> 62)) & ((c >> 2) | (r << 62));
}
__device__ __forceinline__ u64 hshift5_or(u64 c, u64 l, u64 r){
  return hshift3_or(c, l, r) | (c << 2) | (l >> 62) | (c >> 2) | (r << 62);
}

// ---------------- LDS union-find (slab-local, path halving) ---------------
__device__ __forceinline__ int lfind(int* lp, int p){
  while (true){
    int q = lp[p];
    int g = lp[q];
    if (q == g) return q;
    atomicMin(&lp[p], g);
    p = g;
  }
}
__device__ __forceinline__ void lunion(int* lp, int a, int b){
  while (true){
    a = lfind(lp, a);
    b = lfind(lp, b);
    if (a == b) return;
    if (a < b){ int t = a; a = b; b = t; }
    int old = atomicMin(&lp[a], b);
    if (old == a) return;
    a = old;
  }
}

// ------- fused threshold + open (erode3+dilate3) + runs + slab-local UF ---
// Phase R parallelized: the m-th run-start pairs with the m-th run-end in
// scan order (runs never nest), so 8 threads/row each own one word, get
// their global run index via prefix popcount, and scatter start(lo16)/
// end(hi16) into zeroed lruns via LDS atomicOr. Global run metadata is
// written by a cooperative coalesced sweep (was: serial per-run stores
// from 16 threads).
#define ORPB 16
#define TPR (256/ORPB)         // 16 threads per row in L/W phases
#define SLABN (ORPB*RS)        // 2048 run slots per slab
__global__ __launch_bounds__(256)
void k_thropen(const float* __restrict__ x, uint32_t* __restrict__ runs,
               int* __restrict__ cnt, int* __restrict__ parent,
               int* __restrict__ area, int* __restrict__ clabel,
               int* __restrict__ rootcnt){
  __shared__ u64 thr[ORPB + 4][WPRP];  // phase T: thresh rows; phase D+: dl rows
  __shared__ u64 er[ORPB + 2][WPRP];   // y0-1 .. y0+16
  __shared__ uint32_t lruns[ORPB][RSP];
  __shared__ int lcnt[ORPB];
  __shared__ int lparent[SLABN];
  int R0 = blockIdx.x * ORPB;
  int img = R0 >> 9;
  int y0 = R0 & (HH - 1);
  int wid  = threadIdx.x >> 6;
  int lane = threadIdx.x & 63;
  if (blockIdx.x == 0 && threadIdx.x < BB) rootcnt[threadIdx.x] = 0;

  // phase T: (ORPB+4)/2 = 10 row-pairs over 4 waves (ballot-pack)
  for (int pair = wid; pair < (ORPB + 4)/2; pair += 4){
    int lrow = 2*pair + (lane >> 5);          // LDS row 0..19
    int y = y0 - 2 + lrow;                    // image row
    unsigned m = 0;
    if ((unsigned)y < (unsigned)HH){
      const float4* X = reinterpret_cast<const float4*>(
          x + ((size_t)img*HH + y)*WW + (lane & 31)*16);
      #pragma unroll
      for (int q = 0; q < 4; ++q){
        float4 vv = X[q];
        m |= (unsigned)(vv.x > -0.5f) << (q*4 + 0);
        m |= (unsigned)(vv.y > -0.5f) << (q*4 + 1);
        m |= (unsigned)(vv.z > -0.5f) << (q*4 + 2);
        m |= (unsigned)(vv.w > -0.5f) << (q*4 + 3);
      }
    }
    int sub = lane & 3;
    unsigned p1 = __shfl_xor(m, 1);
    unsigned v32 = (sub & 1) ? (p1 | (m << 16)) : (m | (p1 << 16));
    unsigned p2 = __shfl_xor(v32, 2);
    if (sub == 0)
      thr[lrow][(lane >> 2) & 7] = (u64)v32 | ((u64)p2 << 32);
  }
  __syncthreads();

  // phase E: erode3x3 -> er rows j (image row y0-1+j)
  for (int s = threadIdx.x; s < (ORPB + 2)*WPR; s += 256){
    int j = s >> 3;
    int wi = s & 7;
    int rr = y0 - 1 + j;
    u64 acc = ~0ULL;
    #pragma unroll
    for (int dy = 0; dy < 3; ++dy){
      int ti = j + dy;
      u64 c = thr[ti][wi];
      u64 l = (wi > 0) ? thr[ti][wi-1] : 0ULL;
      u64 r = (wi < 7) ? thr[ti][wi+1] : 0ULL;
      acc &= hshift3_and(c, l, r);
    }
    if ((unsigned)rr >= (unsigned)HH) acc = 0ULL;
    er[j][wi] = acc;
  }
  __syncthreads();

  // phase D: dilate3x3 -> thr[ri] (thr dead after E; aliasing saves LDS)
  for (int s = threadIdx.x; s < ORPB*WPR; s += 256){
    int ri = s >> 3;
    int wi = s & 7;
    u64 acc = 0ULL;
    #pragma unroll
    for (int dy = 0; dy < 3; ++dy){
      int li = ri + dy;
      u64 c = er[li][wi];
      u64 l = (wi > 0) ? er[li][wi-1] : 0ULL;
      u64 r = (wi < 7) ? er[li][wi+1] : 0ULL;
      acc |= hshift3_or(c, l, r);
    }
    thr[ri][wi] = acc;
  }

  // init local parent (identity) + zero lruns (scatter targets)
  for (int i = threadIdx.x; i < SLABN; i += 256) lparent[i] = i;
  for (int i = threadIdx.x; i < ORPB*RSP; i += 256)
    (&lruns[0][0])[i] = 0u;
  __syncthreads();                 // dl (thr) + lruns zero visible

  // phase R (parallel): 8 threads per row, one word each
  {
    int ri = threadIdx.x / TPR;
    int wj = threadIdx.x % TPR;
    if (wj < 8){
      u64 b  = thr[ri][wj];
      u64 bp = (wj > 0) ? thr[ri][wj-1] : 0ULL;
      u64 bn = (wj < 7) ? thr[ri][wj+1] : 0ULL;
      u64 starts = b & ~((b << 1) | (bp >> 63));
      u64 ends   = b & ~(b >> 1);
      if (bn & 1ULL) ends &= ~(1ULL << 63);
      // prefix run-index via popcounts over preceding words
      int ps = 0, pe = 0;
      for (int w = 0; w < wj; ++w){
        u64 bw  = thr[ri][w];
        u64 bwp = (w > 0) ? thr[ri][w-1] : 0ULL;
        u64 bwn = thr[ri][w+1];                 // w < wj <= 7
        u64 sw = bw & ~((bw << 1) | (bwp >> 63));
        u64 ew = bw & ~(bw >> 1);
        if (bwn & 1ULL) ew &= ~(1ULL << 63);
        ps += __popcll(sw); pe += __popcll(ew);
      }
      int ne = __popcll(ends);
      while (starts){
        int bit = __ffsll((long long)starts) - 1; starts &= starts - 1;
        atomicOr(&lruns[ri][ps++], (uint32_t)(wj*64 + bit));
      }
      while (ends){
        int bit = __ffsll((long long)ends) - 1; ends &= ends - 1;
        atomicOr(&lruns[ri][pe++], ((uint32_t)(wj*64 + bit)) << 16);
      }
      if (wj == 7) lcnt[ri] = pe;               // pe(before w7) + ne consumed = total
      (void)ne;
    }
  }
  __syncthreads();

  // cooperative global sweep: runs/area/clabel/cnt (coalesced, 256 threads)
  {
    int ri = threadIdx.x / TPR;
    int k0 = threadIdx.x % TPR;
    int r = R0 + ri, base = r*RS;
    int n = lcnt[ri];
    for (int k = k0; k < n; k += TPR){
      int id = base + k;
      runs[id] = lruns[ri][k];
      area[id] = 0; clabel[id] = 0;
    }
    if (k0 == 0) cnt[r] = n;
  }

  // phase L: local link rows 1..ORPB-1 (TPR threads per row)
  {
    int ri = threadIdx.x / TPR;
    int k0 = threadIdx.x % TPR;
    if (ri > 0){
      int ca = lcnt[ri], cb = lcnt[ri-1];
      if (cb > 0){
        for (int k = k0; k < ca; k += TPR){
          uint32_t ra = lruns[ri][k]; int sA = (int)(ra & 0xffff), eA = (int)(ra >> 16);
          int lo = 0, hi = cb, target = sA - 1;
          while (lo < hi){
            int mid = (lo + hi) >> 1;
            if ((int)(lruns[ri-1][mid] >> 16) < target) lo = mid + 1; else hi = mid;
          }
          for (int j = lo; j < cb; ++j){
            if ((int)(lruns[ri-1][j] & 0xffff) > eA + 1) break;
            lunion(lparent, ri*RS + k, (ri-1)*RS + j);
          }
        }
      }
    }
  }
  __syncthreads();

  // phase W: write global parent = slab root (global id space)
  {
    int ri = threadIdx.x / TPR;
    int k0 = threadIdx.x % TPR;
    int n = lcnt[ri];
    for (int k = k0; k < n; k += TPR){
      int lid = ri*RS + k;
      parent[R0*RS + lid] = R0*RS + lfind(lparent, lid);
    }
  }
}

// ---------------- global union-find (path halving) ----------------
__device__ __forceinline__ int uf_find(int* parent, int p){
  while (true){
    int q = parent[p];
    int g = parent[q];
    if (q == g) return q;
    atomicMin(&parent[p], g);
    p = g;
  }
}
__device__ __forceinline__ void uf_union(int* parent, int a, int b){
  while (true){
    a = uf_find(parent, a);
    b = uf_find(parent, b);
    if (a == b) return;
    if (a < b){ int t = a; a = b; b = t; }
    int old = atomicMin(&parent[a], b);
    if (old == a) return;
    a = old;
  }
}

// read-only find
__device__ __forceinline__ int ro_find(const int* __restrict__ parent, int p){
  while (true){ int q = parent[p]; if (q == p) return p; p = q; }
}

// ---------------- boundary link: only rows at slab seams ------------------
#define NBND (HH/ORPB - 1)     // 31 per image
__global__ void k_linkb(const uint32_t* __restrict__ runs, const int* __restrict__ cnt,
                        int* __restrict__ parent){
  int t = blockIdx.x*blockDim.x + threadIdx.x;
  int bi = t >> 3, k0 = t & 7;
  if (bi >= BB*NBND) return;
  int img = bi / NBND, j = bi % NBND;
  int r = img*HH + (j + 1)*ORPB;              // top row of slab; link to r-1
  int ca = cnt[r];
  int cb = cnt[r-1];
  if (cb == 0) return;
  const uint32_t* RB = runs + (size_t)(r-1)*RS;
  for (int k = k0; k < ca; k += 8){
    int id = r*RS + k;
    uint32_t ra = runs[id]; int sA = (int)(ra & 0xffff), eA = (int)(ra >> 16);
    int lo = 0, hi = cb, target = sA - 1;
    while (lo < hi){
      int mid = (lo + hi) >> 1;
      if ((int)(RB[mid] >> 16) < target) lo = mid + 1; else hi = mid;
    }
    for (int jj = lo; jj < cb; ++jj){
      uint32_t rb = RB[jj];
      if ((int)(rb & 0xffff) > eA + 1) break;
      uf_union(parent, id, (r-1)*RS + jj);
    }
  }
}

// ---------------- slab accumulate: direct LDS index, no hash --------------
__global__ __launch_bounds__(256)
void k_slabacc(const uint32_t* __restrict__ runs, const int* __restrict__ cnt,
               int* __restrict__ parent, int* __restrict__ area,
               int* __restrict__ clabel){
  __shared__ int larea[SLABN];
  __shared__ int lclab[SLABN];
  for (int i = threadIdx.x; i < SLABN; i += 256){ larea[i] = 0; lclab[i] = 0; }
  __syncthreads();
  int R0 = blockIdx.x * ORPB;
  int base = R0 * RS;
  int y0 = R0 & (HH - 1);
  int ri = threadIdx.x / TPR;          // 0..ORPB-1
  int k0 = threadIdx.x % TPR;
  int r = R0 + ri;
  int n = cnt[r];
  for (int k = k0; k < n; k += TPR){
    int id = r*RS + k;
    uint32_t run = runs[id]; int s = (int)(run & 0xffff), e = (int)(run >> 16);
    int len = e - s + 1;
    int labl = ri*WW + e + 1;          // local label; +y0*WW at flush
    int p = parent[id];
    int lid = p - base;
    if ((unsigned)lid < (unsigned)SLABN){
      atomicAdd(&larea[lid], len);     // LDS atomics, CU-local
      atomicMax(&lclab[lid], labl);
    } else {
      p = ro_find(parent, p);
      atomicAdd(&area[p], len);
      atomicMax(&clabel[p], y0*WW + labl);
    }
  }
  __syncthreads();
  // flush: one global atomic pair per contributing slot
  for (int i = threadIdx.x; i < SLABN; i += 256){
    int la = larea[i];
    if (la == 0) continue;
    int gid = base + i;
    int p = ro_find(parent, gid);
    atomicAdd(&area[p], la);
    atomicMax(&clabel[p], y0*WW + lclab[i]);
    if (p != gid) parent[gid] = p;     // shortcut to final root (monotone)
  }
}

// ---------------- compact roots per image ----------------
__global__ void k_roots(const int* __restrict__ cnt, const int* __restrict__ parent,
                        const int* __restrict__ area, const int* __restrict__ clabel,
                        int* __restrict__ rootcnt, int* __restrict__ rootA,
                        int* __restrict__ rootL){
  int t = blockIdx.x*blockDim.x + threadIdx.x;
  if (t >= NROWS*KPR) return;
  int r = t / KPR, k0 = t % KPR;
  int n = cnt[r];
  int b = r >> 9;
  for (int k = k0; k < n; k += KPR){
    int id = r*RS + k;
    if (parent[id] != id) continue;          // global roots only
    int a = area[id];
    if (a < 200) continue;                   // MIN_AREA
    int idx = atomicAdd(&rootcnt[b], 1);
    rootA[b*MAXROOTS + idx] = a;
    rootL[b*MAXROOTS + idx] = clabel[id];
  }
}

// ---------------- top-2 per image (area desc, label asc tie) --------------
__device__ __forceinline__ void ins2(int v, int i, int& v1, int& i1, int& v2, int& i2){
  if (v > v1 || (v == v1 && i < i1)) { v2 = v1; i2 = i1; v1 = v; i1 = i; }
  else if (v > v2 || (v == v2 && i < i2)) { v2 = v; i2 = i; }
}

__global__ void k_top2(const int* __restrict__ rootcnt, const int* __restrict__ rootA,
                       const int* __restrict__ rootL, int* __restrict__ keepL){
  __shared__ int sv1[64], si1[64], sv2[64], si2[64];
  int b = blockIdx.x;
  int n = rootcnt[b];
  int v1 = 0, i1 = INT_MAX, v2 = 0, i2 = INT_MAX;
  for (int k = threadIdx.x; k < n; k += 64)
    ins2(rootA[b*MAXROOTS + k], rootL[b*MAXROOTS + k], v1, i1, v2, i2);
  int t = threadIdx.x;
  sv1[t] = v1; si1[t] = i1; sv2[t] = v2; si2[t] = i2;
  __syncthreads();
  for (int s = 32; s > 0; s >>= 1){
    if (t < s){
      int a1 = sv1[t], b1 = si1[t], a2 = sv2[t], b2 = si2[t];
      ins2(sv1[t+s], si1[t+s], a1, b1, a2, b2);
      ins2(sv2[t+s], si2[t+s], a1, b1, a2, b2);
      sv1[t] = a1; si1[t] = b1; sv2[t] = a2; si2[t] = b2;
    }
    __syncthreads();
  }
  if (t == 0){
    keepL[b*2 + 0] = (sv1[0] > 0) ? si1[0] : 0;   // 0 invalid (labels >= 1)
    keepL[b*2 + 1] = (sv2[0] > 0) ? si2[0] : 0;
  }
}

// ---------------- fused keep-build + close (dilate5+erode5) + expand ------
__device__ __forceinline__ u64 rmask(int s, int e){  // bits s..e inclusive
  u64 hi = (e >= 63) ? ~0ULL : ((1ULL << (e + 1)) - 1);
  u64 lo = (1ULL << s) - 1;
  return hi & ~lo;
}

#define CRPB 16                // 2048 blocks -> 32 waves/CU grid cap
__global__ __launch_bounds__(256)
void k_closeexpand(const uint32_t* __restrict__ runs, const int* __restrict__ cnt,
                   const int* __restrict__ parent, const int* __restrict__ clabel,
                   const int* __restrict__ keepL, float* __restrict__ out){
  __shared__ u64 kp[CRPB + 8][WPR];   // keep rows y0-4 .. y0+19
  __shared__ u64 dil[CRPB + 4][WPR];  // dilated rows y0-2 .. y0+17
  __shared__ u64 ero[CRPB][WPR];
  __shared__ int scnt[CRPB + 8];
  int R0 = blockIdx.x * CRPB;
  int img = R0 >> 9;
  int y0 = R0 & (HH - 1);
  int L1 = keepL[img*2], L2 = keepL[img*2 + 1];
  // phase 0a: zero kp + stage per-row counts
  for (int i = threadIdx.x; i < (CRPB + 8)*WPR; i += 256)
    kp[i >> 3][i & 7] = 0ULL;
  if (threadIdx.x < CRPB + 8){
    int y = y0 + threadIdx.x - 4;
    scnt[threadIdx.x] = ((unsigned)y < (unsigned)HH) ? cnt[img*HH + y] : 0;
  }
  __syncthreads();
  // phase 0b: build keep bits, 8 threads per row; LDS atomicOr commit
  for (int rr = threadIdx.x >> 3; rr < CRPB + 8; rr += 32){
    int y = y0 + rr - 4;
    int row = img*HH + y;
    int n = scnt[rr];
    for (int k = threadIdx.x & 7; k < n; k += 8){
      int id = row*RS + k;
      int p = parent[id];
      while (true){ int q = parent[p]; if (q == p) break; p = q; }  // depth<=3
      int L = clabel[p];
      if (L != L1 && L != L2) continue;
      uint32_t run = runs[id]; int st = (int)(run & 0xffff), e = (int)(run >> 16);
      int w0 = st >> 6, w1 = e >> 6;
      if (w0 == w1) atomicOr(&kp[rr][w0], rmask(st & 63, e & 63));
      else {
        atomicOr(&kp[rr][w0], rmask(st & 63, 63));
        for (int wi = w0 + 1; wi < w1; ++wi) atomicOr(&kp[rr][wi], ~0ULL);
        atomicOr(&kp[rr][w1], rmask(0, e & 63));
      }
    }
  }
  __syncthreads();
  // phase 1: dilate5 rows y0-2 .. y0+CRPB+1
  for (int s = threadIdx.x; s < (CRPB + 4)*WPR; s += 256){
    int li = s >> 3;
    int wi = s & 7;
    u64 acc = 0ULL;
    #pragma unroll
    for (int dy = -2; dy <= 2; ++dy){
      int ki = li + 2 + dy;
      u64 c = kp[ki][wi];
      u64 l = (wi > 0) ? kp[ki][wi-1] : 0ULL;
      u64 r = (wi < 7) ? kp[ki][wi+1] : 0ULL;
      acc |= hshift5_or(c, l, r);
    }
    dil[li][wi] = acc;
  }
  __syncthreads();
  // phase 2: erode5 center rows (zero pad outside image)
  for (int s = threadIdx.x; s < CRPB*WPR; s += 256){
    int ri = s >> 3;
    int wi = s & 7;
    int y = y0 + ri;
    u64 acc = ~0ULL;
    #pragma unroll
    for (int dy = -2; dy <= 2; ++dy){
      int yy = y + dy;
      u64 h;
      if ((unsigned)yy >= (unsigned)HH) h = 0ULL;
      else {
        int li = ri + 2 + dy;
        u64 c = dil[li][wi];
        u64 l = (wi > 0) ? dil[li][wi-1] : 0ULL;
        u64 r = (wi < 7) ? dil[li][wi+1] : 0ULL;
        h = hshift5_and(c, l, r);
      }
      acc &= h;
    }
    ero[ri][wi] = acc;
  }
  __syncthreads();
  // phase 3: expand to f32, coalesced float4 stores
  float4* O = reinterpret_cast<float4*>(out + (size_t)R0*WW);
  for (int i = threadIdx.x; i < CRPB*WW/4; i += 256){
    int px = i * 4;
    int row = px >> 9;
    int x = px & (WW - 1);
    u64 word = ero[row][x >> 6];
    unsigned nib = (unsigned)((word >> (x & 63)) & 0xFULL);
    float4 f;
    f.x = (float)( nib       & 1);
    f.y = (float)((nib >> 1) & 1);
    f.z = (float)((nib >> 2) & 1);
    f.w = (float)((nib >> 3) & 1);
    O[i] = f;
  }
}

// ---------------- launch ----------------
extern "C" void kernel_launch(void* const* d_in, const int* in_sizes, int n_in,
                              void* d_out, int out_size, void* d_ws, size_t ws_size,
                              hipStream_t stream){
  const float* x = (const float*)d_in[0];
  float* out = (float*)d_out;
  char* ws = (char*)d_ws;

  const size_t RUNS_OFF    = 0;                         // 16 MiB
  const size_t PAR_OFF     = RUNS_OFF   + (size_t)MAXRUNS*4;
  const size_t AREA_OFF    = PAR_OFF    + (size_t)MAXRUNS*4;
  const size_t CLAB_OFF    = AREA_OFF   + (size_t)MAXRUNS*4;
  const size_t CNT_OFF     = CLAB_OFF   + (size_t)MAXRUNS*4;
  const size_t RCNT_OFF    = CNT_OFF    + (size_t)NROWS*4;
  const size_t RA_OFF      = RCNT_OFF   + 1024ull;
  const size_t RL_OFF      = RA_OFF     + (size_t)BB*MAXROOTS*4;
  const size_t KEEPL_OFF   = RL_OFF     + (size_t)BB*MAXROOTS*4;

  uint32_t* runs     = (uint32_t*)(ws + RUNS_OFF);
  int*      parent   = (int*)(ws + PAR_OFF);
  int*      area     = (int*)(ws + AREA_OFF);
  int*      clabel   = (int*)(ws + CLAB_OFF);
  int*      cnt      = (int*)(ws + CNT_OFF);
  int*      rootcnt  = (int*)(ws + RCNT_OFF);
  int*      rootA    = (int*)(ws + RA_OFF);
  int*      rootL    = (int*)(ws + RL_OFF);
  int*      keepL    = (int*)(ws + KEEPL_OFF);

  const int T = 256;
  dim3 blk(T);

  // 1) fused threshold + open + runs (parallel) + slab-local UF
  k_thropen<<<dim3(NROWS/ORPB), blk, 0, stream>>>(x, runs, cnt, parent, area,
                                                  clabel, rootcnt);
  // 2) boundary link (1984 seam rows)
  k_linkb<<<dim3((BB*NBND*8 + T - 1)/T), blk, 0, stream>>>(runs, cnt, parent);
  // 3) slab accumulate (direct LDS index)
  k_slabacc<<<dim3(NROWS/ORPB), blk, 0, stream>>>(runs, cnt, parent, area, clabel);
  // 4) compact roots
  k_roots<<<dim3(NROWS*KPR/T), blk, 0, stream>>>(cnt, parent, area, clabel,
                                                 rootcnt, rootA, rootL);
  // 5) top-2 per image over compacted candidates
  k_top2<<<dim3(BB), dim3(64), 0, stream>>>(rootcnt, rootA, rootL, keepL);
  // 6) fused keep-build + close + expand -> f32 out (2048 blocks)
  k_closeexpand<<<dim3(NROWS/CRPB), blk, 0, stream>>>(runs, cnt, parent, clabel,
                                                      keepL, out);

  (void)in_sizes; (void)n_in; (void)out_size; (void)ws_size;
}